// Round 12
// baseline (310.415 us; speedup 1.0000x reference)
//
#include <hip/hip_runtime.h>

#define NN 100000
#define NE 1200000
#define CH 64
#define NREL 5
#define NCLS 8
#define SLOT 64      // max in-degree tracked; deg ~ Poisson(12), P(>64) ~ 1e-30
#define KTOT 384     // 6*64 (root + 5 relations)
#define HPAD 66      // padded h-stage stride (floats)

typedef _Float16 f16;
typedef _Float16 f16x4 __attribute__((ext_vector_type(4)));
typedef _Float16 f16x8 __attribute__((ext_vector_type(8)));
typedef float f32x4 __attribute__((ext_vector_type(4)));

#define RFL __builtin_amdgcn_readfirstlane

// ---- fused: blocks [0,cvtB) convert x->f16; blocks [cvtB,..) scatter edges ----
__global__ __launch_bounds__(256) void cvt_scatter_kernel(
    const float* __restrict__ x, f16* __restrict__ xh,
    const int* __restrict__ src, const int* __restrict__ dst,
    const int* __restrict__ et, int* __restrict__ cursor,
    int* __restrict__ sorted, int cvtB) {
    if ((int)blockIdx.x < cvtB) {
        int t = blockIdx.x * 256 + threadIdx.x;
        if (t >= NN * CH / 4) return;
        float4 v = reinterpret_cast<const float4*>(x)[t];
        f16x4 h = {(f16)v.x, (f16)v.y, (f16)v.z, (f16)v.w};
        *reinterpret_cast<f16x4*>(xh + (size_t)t * 4) = h;
    } else {
        int e = (blockIdx.x - cvtB) * 256 + threadIdx.x;
        if (e >= NE) return;
        int d = dst[e];
        int pos = atomicAdd(&cursor[d], 1);
        if (pos < SLOT) sorted[(size_t)d * SLOT + pos] = src[e] | (et[e] << 17);
    }
}

// ---- convert weights to f16 B^T layout: Btg[layer][n][k] ----
__global__ __launch_bounds__(256) void prep_weights(const float* __restrict__ root1,
                                                    const float* __restrict__ W1,
                                                    const float* __restrict__ root2,
                                                    const float* __restrict__ W2,
                                                    f16* __restrict__ Btg) {
    int o = blockIdx.x * 256 + threadIdx.x;
    if (o >= 2 * 64 * KTOT) return;
    int layer = o / (64 * KTOT);
    int rem = o % (64 * KTOT);
    int n = rem / KTOT, k = rem % KTOT;
    const float* R = layer ? root2 : root1;
    const float* W = layer ? W2 : W1;
    float v = (k < CH) ? R[k * CH + n] : W[(size_t)(k - CH) * CH + n];
    Btg[o] = (f16)v;
}

// One block = 16 nodes, 256 threads (4 waves), ~12.5 KB LDS -> 8 blocks/CU.
// Phase 1: wave gathers 4 nodes; 16 edge-row loads issued per burst (covers a
//   typical deg-12 node in one shot); in-order vmcnt consumption overlaps the
//   accumulate ladder with the remaining loads in flight.
// Phase 2: wave w computes N-tile w: 12x mfma_16x16x32_f16; A from LDS, B from
//   global (48 KB panel, L2-resident across all blocks).
template<bool CLS>
__global__ __launch_bounds__(256, 8) void fused_layer2(
    const f16* __restrict__ in, const f16* __restrict__ Btg,
    const float* __restrict__ bias,
    const int* __restrict__ cursor, const int* __restrict__ sorted,
    float* __restrict__ outf, f16* __restrict__ outh,
    const float* __restrict__ Wc, const float* __restrict__ bc,
    float* __restrict__ logits) {
    __shared__ __align__(16) char smem[16 * 784];
    f16* Ap = (f16*)smem;

    const int tid = threadIdx.x;
    const int wv = tid >> 6, lane = tid & 63;
    const int wvu = RFL(wv);
    const int nb0 = blockIdx.x * 16;

    // ---- phase 1: gather 4 nodes per wave ----
    for (int q = 0; q < 4; ++q) {
        int nl = wvu * 4 + q;
        int i = nb0 + nl;
        f16* arow = Ap + nl * 392;
        if (i >= NN) {
#pragma unroll
            for (int m = 0; m < 6; ++m) arow[m * 64 + lane] = (f16)0.f;
            continue;
        }
        int deg = cursor[i];
        if (deg > SLOT) deg = SLOT;
        const int* sp = sorted + (size_t)i * SLOT;

        float self = (float)in[(size_t)i * CH + lane];
        float a0 = 0.f, a1 = 0.f, a2 = 0.f, a3 = 0.f, a4 = 0.f;
        int c0 = 0, c1 = 0, c2 = 0, c3 = 0, c4 = 0;

        // 16 edges per burst: 4x int4 word loads + 16 row loads all in flight
        for (int e0 = 0; e0 < deg; e0 += 16) {
            int4 pka = *(const int4*)(sp + e0);
            int4 pkb = *(const int4*)(sp + e0 + 4);
            int4 pkc = *(const int4*)(sp + e0 + 8);     // 16-int slack after
            int4 pkd = *(const int4*)(sp + e0 + 12);    // sorted -> in-bounds
            int p0 = RFL(pka.x), p1 = RFL(pka.y), p2 = RFL(pka.z), p3 = RFL(pka.w);
            int p4 = RFL(pkb.x), p5 = RFL(pkb.y), p6 = RFL(pkb.z), p7 = RFL(pkb.w);
            int p8 = RFL(pkc.x), p9 = RFL(pkc.y), pA = RFL(pkc.z), pB = RFL(pkc.w);
            int pC = RFL(pkd.x), pD = RFL(pkd.y), pE = RFL(pkd.z), pF = RFL(pkd.w);
#define SIDX(J, PJ) uint s##J = (e0 + 0x##J < deg) ? ((uint)(PJ) & 0x1FFFF) : (uint)i;
            SIDX(0, p0) SIDX(1, p1) SIDX(2, p2) SIDX(3, p3)
            SIDX(4, p4) SIDX(5, p5) SIDX(6, p6) SIDX(7, p7)
            SIDX(8, p8) SIDX(9, p9) SIDX(A, pA) SIDX(B, pB)
            SIDX(C, pC) SIDX(D, pD) SIDX(E, pE) SIDX(F, pF)
#undef SIDX
            // issue all 16 row loads before any consumption
            float v0 = (float)in[(size_t)s0 * CH + lane];
            float v1 = (float)in[(size_t)s1 * CH + lane];
            float v2 = (float)in[(size_t)s2 * CH + lane];
            float v3 = (float)in[(size_t)s3 * CH + lane];
            float v4 = (float)in[(size_t)s4 * CH + lane];
            float v5 = (float)in[(size_t)s5 * CH + lane];
            float v6 = (float)in[(size_t)s6 * CH + lane];
            float v7 = (float)in[(size_t)s7 * CH + lane];
            float v8 = (float)in[(size_t)s8 * CH + lane];
            float v9 = (float)in[(size_t)s9 * CH + lane];
            float vA = (float)in[(size_t)sA * CH + lane];
            float vB = (float)in[(size_t)sB * CH + lane];
            float vC = (float)in[(size_t)sC * CH + lane];
            float vD = (float)in[(size_t)sD * CH + lane];
            float vE = (float)in[(size_t)sE * CH + lane];
            float vF = (float)in[(size_t)sF * CH + lane];
#define LAD(J, PJ, VJ)                                                          \
            if (e0 + 0x##J < deg) {                                             \
                int r = (PJ) >> 17;                                             \
                if (r == 0)      { a0 += (VJ); c0++; }                          \
                else if (r == 1) { a1 += (VJ); c1++; }                          \
                else if (r == 2) { a2 += (VJ); c2++; }                          \
                else if (r == 3) { a3 += (VJ); c3++; }                          \
                else             { a4 += (VJ); c4++; }                          \
            }
            LAD(0, p0, v0) LAD(1, p1, v1) LAD(2, p2, v2) LAD(3, p3, v3)
            LAD(4, p4, v4) LAD(5, p5, v5) LAD(6, p6, v6) LAD(7, p7, v7)
            LAD(8, p8, v8) LAD(9, p9, v9) LAD(A, pA, vA) LAD(B, pB, vB)
            LAD(C, pC, vC) LAD(D, pD, vD) LAD(E, pE, vE) LAD(F, pF, vF)
#undef LAD
        }

        float i0 = 1.0f / (float)(c0 > 0 ? c0 : 1);
        float i1 = 1.0f / (float)(c1 > 0 ? c1 : 1);
        float i2 = 1.0f / (float)(c2 > 0 ? c2 : 1);
        float i3 = 1.0f / (float)(c3 > 0 ? c3 : 1);
        float i4 = 1.0f / (float)(c4 > 0 ? c4 : 1);

        arow[0 * 64 + lane] = (f16)self;
        arow[1 * 64 + lane] = (f16)(a0 * i0);
        arow[2 * 64 + lane] = (f16)(a1 * i1);
        arow[3 * 64 + lane] = (f16)(a2 * i2);
        arow[4 * 64 + lane] = (f16)(a3 * i3);
        arow[5 * 64 + lane] = (f16)(a4 * i4);
    }
    __syncthreads();

    // ---- phase 2: MFMA. wave w -> N-tile w (cols w*16..w*16+15) ----
    const int col = lane & 15, lg = lane >> 4;
    float bv = bias[wvu * 16 + col];
    f32x4 acc = {bv, bv, bv, bv};
    const char* Ab = (const char*)Ap + col * 784 + lg * 16;
    const char* Bb = (const char*)Btg + (size_t)(wvu * 16 + col) * 768 + lg * 16;
#pragma unroll
    for (int k = 0; k < KTOT / 32; ++k) {
        f16x8 af = *(const f16x8*)(Ab + k * 64);
        f16x8 bf = *(const f16x8*)(Bb + k * 64);
        acc = __builtin_amdgcn_mfma_f32_16x16x32_f16(af, bf, acc, 0, 0, 0);
    }

    if (!CLS) {
#pragma unroll
        for (int r = 0; r < 4; ++r) {
            int node = nb0 + lg * 4 + r;
            if (node < NN)
                outh[(size_t)node * CH + wvu * 16 + col] = (f16)fmaxf(acc[r], 0.f);
        }
    } else {
        __syncthreads();  // all Ap reads done -> reuse smem as h-stage
        float* hst = (float*)smem;  // [16][HPAD]
#pragma unroll
        for (int r = 0; r < 4; ++r) {
            int nl = lg * 4 + r;
            int node = nb0 + nl;
            hst[nl * HPAD + wvu * 16 + col] = acc[r];
            if (node < NN)
                outf[(size_t)node * CH + wvu * 16 + col] = acc[r];
        }
        __syncthreads();
        float wcr[NCLS];
#pragma unroll
        for (int c = 0; c < NCLS; ++c) wcr[c] = Wc[lane * NCLS + c];
        for (int q = 0; q < 4; ++q) {
            int nl = wvu * 4 + q;
            int i = nb0 + nl;
            if (i >= NN) continue;
            float v = hst[nl * HPAD + lane];
            float p[NCLS];
#pragma unroll
            for (int c = 0; c < NCLS; ++c) p[c] = v * wcr[c];
#pragma unroll
            for (int off = 32; off > 0; off >>= 1) {
#pragma unroll
                for (int c = 0; c < NCLS; ++c) p[c] += __shfl_xor(p[c], off);
            }
            if (lane == 0) {
                float4 lo = make_float4(p[0] + bc[0], p[1] + bc[1], p[2] + bc[2], p[3] + bc[3]);
                float4 hi = make_float4(p[4] + bc[4], p[5] + bc[5], p[6] + bc[6], p[7] + bc[7]);
                *reinterpret_cast<float4*>(&logits[(size_t)i * NCLS]) = lo;
                *reinterpret_cast<float4*>(&logits[(size_t)i * NCLS + 4]) = hi;
            }
        }
    }
}

extern "C" void kernel_launch(void* const* d_in, const int* in_sizes, int n_in,
                              void* d_out, int out_size, void* d_ws, size_t ws_size,
                              hipStream_t stream) {
    const float* x     = (const float*)d_in[0];
    const int*   ei    = (const int*)d_in[1];
    const int*   et    = (const int*)d_in[2];
    const float* W1    = (const float*)d_in[3];
    const float* root1 = (const float*)d_in[4];
    const float* b1    = (const float*)d_in[5];
    const float* W2    = (const float*)d_in[6];
    const float* root2 = (const float*)d_in[7];
    const float* b2    = (const float*)d_in[8];
    const float* Wc    = (const float*)d_in[9];
    const float* bc    = (const float*)d_in[10];
    const int* src = ei;
    const int* dst = ei + NE;

    float* h2     = (float*)d_out;            // [NN][CH]
    float* logits = h2 + (size_t)NN * CH;     // [NN][NCLS]

    int* cursor = (int*)d_ws;                                   // [NN]
    int* sorted = cursor + NN;                                  // [NN][SLOT] + 16 slack
    f16* h1h    = (f16*)(sorted + (size_t)NN * SLOT + 16);      // [NN][CH]
    f16* xh     = h1h + (size_t)NN * CH;                        // [NN][CH]
    f16* Btg    = xh + (size_t)NN * CH;                         // [2][64][KTOT]

    (void)hipMemsetAsync(cursor, 0, (size_t)NN * 4, stream);
    int cvtB = (NN * CH / 4 + 255) / 256;
    int sctB = (NE + 255) / 256;
    cvt_scatter_kernel<<<cvtB + sctB, 256, 0, stream>>>(x, xh, src, dst, et, cursor, sorted, cvtB);
    prep_weights<<<(2 * 64 * KTOT + 255) / 256, 256, 0, stream>>>(root1, W1, root2, W2, Btg);

    int nBlk = (NN + 15) / 16;  // 6250
    fused_layer2<false><<<nBlk, 256, 0, stream>>>(
        xh, Btg, b1, cursor, sorted, nullptr, h1h, nullptr, nullptr, nullptr);
    fused_layer2<true><<<nBlk, 256, 0, stream>>>(
        h1h, Btg + (size_t)64 * KTOT, b2, cursor, sorted, h2, nullptr, Wc, bc, logits);
}

// Round 13
// 300.241 us; speedup vs baseline: 1.0339x; 1.0339x over previous
//
#include <hip/hip_runtime.h>

#define NN 100000
#define NE 1200000
#define CH 64
#define NREL 5
#define NCLS 8
#define SLOT 64      // max in-degree tracked; deg ~ Poisson(12), P(>64) ~ 1e-30
#define KTOT 384     // 6*64 (root + 5 relations)
#define HPAD 66      // padded h-stage stride (floats)

typedef _Float16 f16;
typedef _Float16 f16x4 __attribute__((ext_vector_type(4)));
typedef _Float16 f16x8 __attribute__((ext_vector_type(8)));
typedef float f32x4 __attribute__((ext_vector_type(4)));

#define RFL __builtin_amdgcn_readfirstlane

// ---- fused: blocks [0,cvtB) convert x->f16; blocks [cvtB,..) scatter edges ----
__global__ __launch_bounds__(256) void cvt_scatter_kernel(
    const float* __restrict__ x, f16* __restrict__ xh,
    const int* __restrict__ src, const int* __restrict__ dst,
    const int* __restrict__ et, int* __restrict__ cursor,
    int* __restrict__ sorted, int cvtB) {
    if ((int)blockIdx.x < cvtB) {
        int t = blockIdx.x * 256 + threadIdx.x;
        if (t >= NN * CH / 4) return;
        float4 v = reinterpret_cast<const float4*>(x)[t];
        f16x4 h = {(f16)v.x, (f16)v.y, (f16)v.z, (f16)v.w};
        *reinterpret_cast<f16x4*>(xh + (size_t)t * 4) = h;
    } else {
        int e = (blockIdx.x - cvtB) * 256 + threadIdx.x;
        if (e >= NE) return;
        int d = dst[e];
        int pos = atomicAdd(&cursor[d], 1);
        if (pos < SLOT) sorted[(size_t)d * SLOT + pos] = src[e] | (et[e] << 17);
    }
}

// ---- convert weights to f16 B^T layout: Btg[layer][n][k] ----
__global__ __launch_bounds__(256) void prep_weights(const float* __restrict__ root1,
                                                    const float* __restrict__ W1,
                                                    const float* __restrict__ root2,
                                                    const float* __restrict__ W2,
                                                    f16* __restrict__ Btg) {
    int o = blockIdx.x * 256 + threadIdx.x;
    if (o >= 2 * 64 * KTOT) return;
    int layer = o / (64 * KTOT);
    int rem = o % (64 * KTOT);
    int n = rem / KTOT, k = rem % KTOT;
    const float* R = layer ? root2 : root1;
    const float* W = layer ? W2 : W1;
    float v = (k < CH) ? R[k * CH + n] : W[(size_t)(k - CH) * CH + n];
    Btg[o] = (f16)v;
}

// One block = 16 nodes, 256 threads (4 waves), ~12.5 KB LDS -> 8 blocks/CU.
// Phase 1: wave gathers 4 nodes with R9's proven 8-deep pipelined edge loop;
//   all 4 node degrees + self rows prefetched upfront to bridge inter-node
//   latency chains.
// Phase 2: wave w computes N-tile w: 12x mfma_16x16x32_f16; A from LDS, B from
//   global (48 KB panel, L2-resident across all blocks).
template<bool CLS>
__global__ __launch_bounds__(256, 8) void fused_layer2(
    const f16* __restrict__ in, const f16* __restrict__ Btg,
    const float* __restrict__ bias,
    const int* __restrict__ cursor, const int* __restrict__ sorted,
    float* __restrict__ outf, f16* __restrict__ outh,
    const float* __restrict__ Wc, const float* __restrict__ bc,
    float* __restrict__ logits) {
    __shared__ __align__(16) char smem[16 * 784];
    f16* Ap = (f16*)smem;

    const int tid = threadIdx.x;
    const int wv = tid >> 6, lane = tid & 63;
    const int wvu = RFL(wv);
    const int nb0 = blockIdx.x * 16;

    // ---- upfront: all 4 node degrees + self rows (independent loads) ----
    int degs[4];
    float selfs[4];
#pragma unroll
    for (int q = 0; q < 4; ++q) {
        int i = nb0 + wvu * 4 + q;
        degs[q] = (i < NN) ? cursor[i] : 0;
        selfs[q] = (i < NN) ? (float)in[(size_t)i * CH + lane] : 0.f;
    }

    // ---- phase 1: gather 4 nodes per wave (R9 8-deep loop) ----
#pragma unroll
    for (int q = 0; q < 4; ++q) {
        int nl = wvu * 4 + q;
        int i = nb0 + nl;
        f16* arow = Ap + nl * 392;
        if (i >= NN) {
#pragma unroll
            for (int m = 0; m < 6; ++m) arow[m * 64 + lane] = (f16)0.f;
            continue;
        }
        int deg = degs[q];
        if (deg > SLOT) deg = SLOT;
        const int* sp = sorted + (size_t)i * SLOT;

        float a0 = 0.f, a1 = 0.f, a2 = 0.f, a3 = 0.f, a4 = 0.f;
        int c0 = 0, c1 = 0, c2 = 0, c3 = 0, c4 = 0;

        if (deg > 0) {
            int4 pka = *(const int4*)sp;
            int4 pkb = *(const int4*)(sp + 4);
            for (int e0 = 0; e0 < deg; e0 += 8) {
                int4 nxa = *(const int4*)(sp + e0 + 8);   // slack guarantees in-bounds
                int4 nxb = *(const int4*)(sp + e0 + 12);
                int p0 = RFL(pka.x), p1 = RFL(pka.y), p2 = RFL(pka.z), p3 = RFL(pka.w);
                int p4 = RFL(pkb.x), p5 = RFL(pkb.y), p6 = RFL(pkb.z), p7 = RFL(pkb.w);
                uint s0 = (e0 + 0 < deg) ? ((uint)p0 & 0x1FFFF) : (uint)i;
                uint s1 = (e0 + 1 < deg) ? ((uint)p1 & 0x1FFFF) : (uint)i;
                uint s2 = (e0 + 2 < deg) ? ((uint)p2 & 0x1FFFF) : (uint)i;
                uint s3 = (e0 + 3 < deg) ? ((uint)p3 & 0x1FFFF) : (uint)i;
                uint s4 = (e0 + 4 < deg) ? ((uint)p4 & 0x1FFFF) : (uint)i;
                uint s5 = (e0 + 5 < deg) ? ((uint)p5 & 0x1FFFF) : (uint)i;
                uint s6 = (e0 + 6 < deg) ? ((uint)p6 & 0x1FFFF) : (uint)i;
                uint s7 = (e0 + 7 < deg) ? ((uint)p7 & 0x1FFFF) : (uint)i;
                float v0 = (float)in[(size_t)s0 * CH + lane];
                float v1 = (float)in[(size_t)s1 * CH + lane];
                float v2 = (float)in[(size_t)s2 * CH + lane];
                float v3 = (float)in[(size_t)s3 * CH + lane];
                float v4 = (float)in[(size_t)s4 * CH + lane];
                float v5 = (float)in[(size_t)s5 * CH + lane];
                float v6 = (float)in[(size_t)s6 * CH + lane];
                float v7 = (float)in[(size_t)s7 * CH + lane];
#define LAD(J, PJ, VJ)                                                          \
                if (e0 + J < deg) {                                             \
                    int r = (PJ) >> 17;                                         \
                    if (r == 0)      { a0 += (VJ); c0++; }                      \
                    else if (r == 1) { a1 += (VJ); c1++; }                      \
                    else if (r == 2) { a2 += (VJ); c2++; }                      \
                    else if (r == 3) { a3 += (VJ); c3++; }                      \
                    else             { a4 += (VJ); c4++; }                      \
                }
                LAD(0, p0, v0) LAD(1, p1, v1) LAD(2, p2, v2) LAD(3, p3, v3)
                LAD(4, p4, v4) LAD(5, p5, v5) LAD(6, p6, v6) LAD(7, p7, v7)
#undef LAD
                pka = nxa; pkb = nxb;
            }
        }

        float i0 = 1.0f / (float)(c0 > 0 ? c0 : 1);
        float i1 = 1.0f / (float)(c1 > 0 ? c1 : 1);
        float i2 = 1.0f / (float)(c2 > 0 ? c2 : 1);
        float i3 = 1.0f / (float)(c3 > 0 ? c3 : 1);
        float i4 = 1.0f / (float)(c4 > 0 ? c4 : 1);

        arow[0 * 64 + lane] = (f16)selfs[q];
        arow[1 * 64 + lane] = (f16)(a0 * i0);
        arow[2 * 64 + lane] = (f16)(a1 * i1);
        arow[3 * 64 + lane] = (f16)(a2 * i2);
        arow[4 * 64 + lane] = (f16)(a3 * i3);
        arow[5 * 64 + lane] = (f16)(a4 * i4);
    }
    __syncthreads();

    // ---- phase 2: MFMA. wave w -> N-tile w (cols w*16..w*16+15) ----
    const int col = lane & 15, lg = lane >> 4;
    float bv = bias[wvu * 16 + col];
    f32x4 acc = {bv, bv, bv, bv};
    const char* Ab = (const char*)Ap + col * 784 + lg * 16;
    const char* Bb = (const char*)Btg + (size_t)(wvu * 16 + col) * 768 + lg * 16;
#pragma unroll
    for (int k = 0; k < KTOT / 32; ++k) {
        f16x8 af = *(const f16x8*)(Ab + k * 64);
        f16x8 bf = *(const f16x8*)(Bb + k * 64);
        acc = __builtin_amdgcn_mfma_f32_16x16x32_f16(af, bf, acc, 0, 0, 0);
    }

    if (!CLS) {
#pragma unroll
        for (int r = 0; r < 4; ++r) {
            int node = nb0 + lg * 4 + r;
            if (node < NN)
                outh[(size_t)node * CH + wvu * 16 + col] = (f16)fmaxf(acc[r], 0.f);
        }
    } else {
        __syncthreads();  // all Ap reads done -> reuse smem as h-stage
        float* hst = (float*)smem;  // [16][HPAD]
#pragma unroll
        for (int r = 0; r < 4; ++r) {
            int nl = lg * 4 + r;
            int node = nb0 + nl;
            hst[nl * HPAD + wvu * 16 + col] = acc[r];
            if (node < NN)
                outf[(size_t)node * CH + wvu * 16 + col] = acc[r];
        }
        __syncthreads();
        float wcr[NCLS];
#pragma unroll
        for (int c = 0; c < NCLS; ++c) wcr[c] = Wc[lane * NCLS + c];
        for (int q = 0; q < 4; ++q) {
            int nl = wvu * 4 + q;
            int i = nb0 + nl;
            if (i >= NN) continue;
            float v = hst[nl * HPAD + lane];
            float p[NCLS];
#pragma unroll
            for (int c = 0; c < NCLS; ++c) p[c] = v * wcr[c];
#pragma unroll
            for (int off = 32; off > 0; off >>= 1) {
#pragma unroll
                for (int c = 0; c < NCLS; ++c) p[c] += __shfl_xor(p[c], off);
            }
            if (lane == 0) {
                float4 lo = make_float4(p[0] + bc[0], p[1] + bc[1], p[2] + bc[2], p[3] + bc[3]);
                float4 hi = make_float4(p[4] + bc[4], p[5] + bc[5], p[6] + bc[6], p[7] + bc[7]);
                *reinterpret_cast<float4*>(&logits[(size_t)i * NCLS]) = lo;
                *reinterpret_cast<float4*>(&logits[(size_t)i * NCLS + 4]) = hi;
            }
        }
    }
}

extern "C" void kernel_launch(void* const* d_in, const int* in_sizes, int n_in,
                              void* d_out, int out_size, void* d_ws, size_t ws_size,
                              hipStream_t stream) {
    const float* x     = (const float*)d_in[0];
    const int*   ei    = (const int*)d_in[1];
    const int*   et    = (const int*)d_in[2];
    const float* W1    = (const float*)d_in[3];
    const float* root1 = (const float*)d_in[4];
    const float* b1    = (const float*)d_in[5];
    const float* W2    = (const float*)d_in[6];
    const float* root2 = (const float*)d_in[7];
    const float* b2    = (const float*)d_in[8];
    const float* Wc    = (const float*)d_in[9];
    const float* bc    = (const float*)d_in[10];
    const int* src = ei;
    const int* dst = ei + NE;

    float* h2     = (float*)d_out;            // [NN][CH]
    float* logits = h2 + (size_t)NN * CH;     // [NN][NCLS]

    int* cursor = (int*)d_ws;                                   // [NN]
    int* sorted = cursor + NN;                                  // [NN][SLOT] + 16 slack
    f16* h1h    = (f16*)(sorted + (size_t)NN * SLOT + 16);      // [NN][CH]
    f16* xh     = h1h + (size_t)NN * CH;                        // [NN][CH]
    f16* Btg    = xh + (size_t)NN * CH;                         // [2][64][KTOT]

    (void)hipMemsetAsync(cursor, 0, (size_t)NN * 4, stream);
    int cvtB = (NN * CH / 4 + 255) / 256;
    int sctB = (NE + 255) / 256;
    cvt_scatter_kernel<<<cvtB + sctB, 256, 0, stream>>>(x, xh, src, dst, et, cursor, sorted, cvtB);
    prep_weights<<<(2 * 64 * KTOT + 255) / 256, 256, 0, stream>>>(root1, W1, root2, W2, Btg);

    int nBlk = (NN + 15) / 16;  // 6250
    fused_layer2<false><<<nBlk, 256, 0, stream>>>(
        xh, Btg, b1, cursor, sorted, nullptr, h1h, nullptr, nullptr, nullptr);
    fused_layer2<true><<<nBlk, 256, 0, stream>>>(
        h1h, Btg + (size_t)64 * KTOT, b2, cursor, sorted, h2, nullptr, Wc, bc, logits);
}

// Round 14
// 277.784 us; speedup vs baseline: 1.1175x; 1.0808x over previous
//
#include <hip/hip_runtime.h>

#define NN 100000
#define NE 1200000
#define CH 64
#define NREL 5
#define NCLS 8
#define SLOT 64      // max in-degree tracked; deg ~ Poisson(12), P(>64) ~ 1e-30
#define KTOT 384     // 6*64 (root + 5 relations)
#define HPAD 66      // padded h-stage stride (floats)

typedef _Float16 f16;
typedef _Float16 f16x4 __attribute__((ext_vector_type(4)));
typedef _Float16 f16x8 __attribute__((ext_vector_type(8)));
typedef float f32x4 __attribute__((ext_vector_type(4)));

#define RFL __builtin_amdgcn_readfirstlane

// ---- fused prep: [0,cvtB) x->f16 | [cvtB,cvtB+sctB) edge scatter x4 | rest: weights ----
__global__ __launch_bounds__(256) void prep_kernel(
    const float* __restrict__ x, f16* __restrict__ xh,
    const int* __restrict__ src, const int* __restrict__ dst,
    const int* __restrict__ et, int* __restrict__ cursor,
    int* __restrict__ sorted,
    const float* __restrict__ root1, const float* __restrict__ W1,
    const float* __restrict__ root2, const float* __restrict__ W2,
    f16* __restrict__ Btg, int cvtB, int sctB) {
    int b = (int)blockIdx.x;
    if (b < cvtB) {
        int t = b * 256 + threadIdx.x;
        if (t >= NN * CH / 4) return;
        float4 v = reinterpret_cast<const float4*>(x)[t];
        f16x4 h = {(f16)v.x, (f16)v.y, (f16)v.z, (f16)v.w};
        *reinterpret_cast<f16x4*>(xh + (size_t)t * 4) = h;
    } else if (b < cvtB + sctB) {
        // 4 edges per thread, int4-vectorized metadata loads
        int e0 = ((b - cvtB) * 256 + threadIdx.x) * 4;
        if (e0 >= NE) return;
        if (e0 + 4 <= NE) {
            int4 s4 = *(const int4*)(src + e0);
            int4 d4 = *(const int4*)(dst + e0);
            int4 t4 = *(const int4*)(et + e0);
            int p0 = atomicAdd(&cursor[d4.x], 1);
            int p1 = atomicAdd(&cursor[d4.y], 1);
            int p2 = atomicAdd(&cursor[d4.z], 1);
            int p3 = atomicAdd(&cursor[d4.w], 1);
            if (p0 < SLOT) sorted[(size_t)d4.x * SLOT + p0] = s4.x | (t4.x << 17);
            if (p1 < SLOT) sorted[(size_t)d4.y * SLOT + p1] = s4.y | (t4.y << 17);
            if (p2 < SLOT) sorted[(size_t)d4.z * SLOT + p2] = s4.z | (t4.z << 17);
            if (p3 < SLOT) sorted[(size_t)d4.w * SLOT + p3] = s4.w | (t4.w << 17);
        } else {
            for (int e = e0; e < NE; ++e) {
                int d = dst[e];
                int pos = atomicAdd(&cursor[d], 1);
                if (pos < SLOT) sorted[(size_t)d * SLOT + pos] = src[e] | (et[e] << 17);
            }
        }
    } else {
        int o = (b - cvtB - sctB) * 256 + threadIdx.x;
        if (o >= 2 * 64 * KTOT) return;
        int layer = o / (64 * KTOT);
        int rem = o % (64 * KTOT);
        int n = rem / KTOT, k = rem % KTOT;
        const float* R = layer ? root2 : root1;
        const float* W = layer ? W2 : W1;
        float v = (k < CH) ? R[k * CH + n] : W[(size_t)(k - CH) * CH + n];
        Btg[o] = (f16)v;
    }
}

// One block = 16 nodes, 256 threads (4 waves), ~12.5 KB LDS -> 8 blocks/CU.
// Phase 1: wave gathers 4 nodes (8-deep pipelined edge loop; degrees + self rows
//   prefetched upfront). Phase 2: wave w -> N-tile w, 12x mfma_16x16x32_f16;
//   A from LDS, B from global (48 KB panel, L2-resident across blocks).
template<bool CLS>
__global__ __launch_bounds__(256, 8) void fused_layer2(
    const f16* __restrict__ in, const f16* __restrict__ Btg,
    const float* __restrict__ bias,
    const int* __restrict__ cursor, const int* __restrict__ sorted,
    float* __restrict__ outf, f16* __restrict__ outh,
    const float* __restrict__ Wc, const float* __restrict__ bc,
    float* __restrict__ logits) {
    __shared__ __align__(16) char smem[16 * 784];
    f16* Ap = (f16*)smem;

    const int tid = threadIdx.x;
    const int wv = tid >> 6, lane = tid & 63;
    const int wvu = RFL(wv);
    const int nb0 = blockIdx.x * 16;

    // ---- upfront: all 4 node degrees + self rows (independent loads) ----
    int degs[4];
    float selfs[4];
#pragma unroll
    for (int q = 0; q < 4; ++q) {
        int i = nb0 + wvu * 4 + q;
        degs[q] = (i < NN) ? cursor[i] : 0;
        selfs[q] = (i < NN) ? (float)in[(size_t)i * CH + lane] : 0.f;
    }

    // ---- phase 1: gather 4 nodes per wave (8-deep loop) ----
#pragma unroll
    for (int q = 0; q < 4; ++q) {
        int nl = wvu * 4 + q;
        int i = nb0 + nl;
        f16* arow = Ap + nl * 392;
        if (i >= NN) {
#pragma unroll
            for (int m = 0; m < 6; ++m) arow[m * 64 + lane] = (f16)0.f;
            continue;
        }
        int deg = degs[q];
        if (deg > SLOT) deg = SLOT;
        const int* sp = sorted + (size_t)i * SLOT;

        float a0 = 0.f, a1 = 0.f, a2 = 0.f, a3 = 0.f, a4 = 0.f;
        int c0 = 0, c1 = 0, c2 = 0, c3 = 0, c4 = 0;

        if (deg > 0) {
            int4 pka = *(const int4*)sp;
            int4 pkb = *(const int4*)(sp + 4);
            for (int e0 = 0; e0 < deg; e0 += 8) {
                int4 nxa = *(const int4*)(sp + e0 + 8);   // slack guarantees in-bounds
                int4 nxb = *(const int4*)(sp + e0 + 12);
                int p0 = RFL(pka.x), p1 = RFL(pka.y), p2 = RFL(pka.z), p3 = RFL(pka.w);
                int p4 = RFL(pkb.x), p5 = RFL(pkb.y), p6 = RFL(pkb.z), p7 = RFL(pkb.w);
                uint s0 = (e0 + 0 < deg) ? ((uint)p0 & 0x1FFFF) : (uint)i;
                uint s1 = (e0 + 1 < deg) ? ((uint)p1 & 0x1FFFF) : (uint)i;
                uint s2 = (e0 + 2 < deg) ? ((uint)p2 & 0x1FFFF) : (uint)i;
                uint s3 = (e0 + 3 < deg) ? ((uint)p3 & 0x1FFFF) : (uint)i;
                uint s4 = (e0 + 4 < deg) ? ((uint)p4 & 0x1FFFF) : (uint)i;
                uint s5 = (e0 + 5 < deg) ? ((uint)p5 & 0x1FFFF) : (uint)i;
                uint s6 = (e0 + 6 < deg) ? ((uint)p6 & 0x1FFFF) : (uint)i;
                uint s7 = (e0 + 7 < deg) ? ((uint)p7 & 0x1FFFF) : (uint)i;
                float v0 = (float)in[(size_t)s0 * CH + lane];
                float v1 = (float)in[(size_t)s1 * CH + lane];
                float v2 = (float)in[(size_t)s2 * CH + lane];
                float v3 = (float)in[(size_t)s3 * CH + lane];
                float v4 = (float)in[(size_t)s4 * CH + lane];
                float v5 = (float)in[(size_t)s5 * CH + lane];
                float v6 = (float)in[(size_t)s6 * CH + lane];
                float v7 = (float)in[(size_t)s7 * CH + lane];
#define LAD(J, PJ, VJ)                                                          \
                if (e0 + J < deg) {                                             \
                    int r = (PJ) >> 17;                                         \
                    if (r == 0)      { a0 += (VJ); c0++; }                      \
                    else if (r == 1) { a1 += (VJ); c1++; }                      \
                    else if (r == 2) { a2 += (VJ); c2++; }                      \
                    else if (r == 3) { a3 += (VJ); c3++; }                      \
                    else             { a4 += (VJ); c4++; }                      \
                }
                LAD(0, p0, v0) LAD(1, p1, v1) LAD(2, p2, v2) LAD(3, p3, v3)
                LAD(4, p4, v4) LAD(5, p5, v5) LAD(6, p6, v6) LAD(7, p7, v7)
#undef LAD
                pka = nxa; pkb = nxb;
            }
        }

        float i0 = 1.0f / (float)(c0 > 0 ? c0 : 1);
        float i1 = 1.0f / (float)(c1 > 0 ? c1 : 1);
        float i2 = 1.0f / (float)(c2 > 0 ? c2 : 1);
        float i3 = 1.0f / (float)(c3 > 0 ? c3 : 1);
        float i4 = 1.0f / (float)(c4 > 0 ? c4 : 1);

        arow[0 * 64 + lane] = (f16)selfs[q];
        arow[1 * 64 + lane] = (f16)(a0 * i0);
        arow[2 * 64 + lane] = (f16)(a1 * i1);
        arow[3 * 64 + lane] = (f16)(a2 * i2);
        arow[4 * 64 + lane] = (f16)(a3 * i3);
        arow[5 * 64 + lane] = (f16)(a4 * i4);
    }
    __syncthreads();

    // ---- phase 2: MFMA. wave w -> N-tile w (cols w*16..w*16+15) ----
    const int col = lane & 15, lg = lane >> 4;
    float bv = bias[wvu * 16 + col];
    f32x4 acc = {bv, bv, bv, bv};
    const char* Ab = (const char*)Ap + col * 784 + lg * 16;
    const char* Bb = (const char*)Btg + (size_t)(wvu * 16 + col) * 768 + lg * 16;
#pragma unroll
    for (int k = 0; k < KTOT / 32; ++k) {
        f16x8 af = *(const f16x8*)(Ab + k * 64);
        f16x8 bf = *(const f16x8*)(Bb + k * 64);
        acc = __builtin_amdgcn_mfma_f32_16x16x32_f16(af, bf, acc, 0, 0, 0);
    }

    if (!CLS) {
#pragma unroll
        for (int r = 0; r < 4; ++r) {
            int node = nb0 + lg * 4 + r;
            if (node < NN)
                outh[(size_t)node * CH + wvu * 16 + col] = (f16)fmaxf(acc[r], 0.f);
        }
    } else {
        __syncthreads();  // all Ap reads done -> reuse smem as h-stage
        float* hst = (float*)smem;  // [16][HPAD]
#pragma unroll
        for (int r = 0; r < 4; ++r) {
            int nl = lg * 4 + r;
            int node = nb0 + nl;
            hst[nl * HPAD + wvu * 16 + col] = acc[r];
            if (node < NN)
                outf[(size_t)node * CH + wvu * 16 + col] = acc[r];
        }
        __syncthreads();
        float wcr[NCLS];
#pragma unroll
        for (int c = 0; c < NCLS; ++c) wcr[c] = Wc[lane * NCLS + c];
        for (int q = 0; q < 4; ++q) {
            int nl = wvu * 4 + q;
            int i = nb0 + nl;
            if (i >= NN) continue;
            float v = hst[nl * HPAD + lane];
            float p[NCLS];
#pragma unroll
            for (int c = 0; c < NCLS; ++c) p[c] = v * wcr[c];
#pragma unroll
            for (int off = 32; off > 0; off >>= 1) {
#pragma unroll
                for (int c = 0; c < NCLS; ++c) p[c] += __shfl_xor(p[c], off);
            }
            if (lane == 0) {
                float4 lo = make_float4(p[0] + bc[0], p[1] + bc[1], p[2] + bc[2], p[3] + bc[3]);
                float4 hi = make_float4(p[4] + bc[4], p[5] + bc[5], p[6] + bc[6], p[7] + bc[7]);
                *reinterpret_cast<float4*>(&logits[(size_t)i * NCLS]) = lo;
                *reinterpret_cast<float4*>(&logits[(size_t)i * NCLS + 4]) = hi;
            }
        }
    }
}

extern "C" void kernel_launch(void* const* d_in, const int* in_sizes, int n_in,
                              void* d_out, int out_size, void* d_ws, size_t ws_size,
                              hipStream_t stream) {
    const float* x     = (const float*)d_in[0];
    const int*   ei    = (const int*)d_in[1];
    const int*   et    = (const int*)d_in[2];
    const float* W1    = (const float*)d_in[3];
    const float* root1 = (const float*)d_in[4];
    const float* b1    = (const float*)d_in[5];
    const float* W2    = (const float*)d_in[6];
    const float* root2 = (const float*)d_in[7];
    const float* b2    = (const float*)d_in[8];
    const float* Wc    = (const float*)d_in[9];
    const float* bc    = (const float*)d_in[10];
    const int* src = ei;
    const int* dst = ei + NE;

    float* h2     = (float*)d_out;            // [NN][CH]
    float* logits = h2 + (size_t)NN * CH;     // [NN][NCLS]

    int* cursor = (int*)d_ws;                                   // [NN]
    int* sorted = cursor + NN;                                  // [NN][SLOT] + 16 slack
    f16* h1h    = (f16*)(sorted + (size_t)NN * SLOT + 16);      // [NN][CH]
    f16* xh     = h1h + (size_t)NN * CH;                        // [NN][CH]
    f16* Btg    = xh + (size_t)NN * CH;                         // [2][64][KTOT]

    (void)hipMemsetAsync(cursor, 0, (size_t)NN * 4, stream);
    int cvtB = (NN * CH / 4 + 255) / 256;            // 6250
    int sctB = (NE / 4 + 255) / 256;                 // 1172
    int wgtB = (2 * 64 * KTOT + 255) / 256;          // 192
    prep_kernel<<<cvtB + sctB + wgtB, 256, 0, stream>>>(
        x, xh, src, dst, et, cursor, sorted, root1, W1, root2, W2, Btg, cvtB, sctB);

    int nBlk = (NN + 15) / 16;  // 6250
    fused_layer2<false><<<nBlk, 256, 0, stream>>>(
        xh, Btg, b1, cursor, sorted, nullptr, h1h, nullptr, nullptr, nullptr);
    fused_layer2<true><<<nBlk, 256, 0, stream>>>(
        h1h, Btg + (size_t)64 * KTOT, b2, cursor, sorted, h2, nullptr, Wc, bc, logits);
}